// Round 7
// baseline (140.602 us; speedup 1.0000x reference)
//
#include <hip/hip_runtime.h>
#include <hip/hip_bf16.h>

typedef __attribute__((ext_vector_type(8))) short short8;
typedef __attribute__((ext_vector_type(4))) float f32x4;
typedef __attribute__((address_space(1))) const void gvoid_t;
typedef __attribute__((address_space(3))) void lvoid_t;

#define NB 4096   // B
#define DD 256    // D
#define TWOB 8192
#define NTILES 2080u   // 64*65/2 symmetric 128x128 tiles
#define GSUM_BLOCKS 16
#define GRID_B (NTILES + GSUM_BLOCKS)

__device__ __forceinline__ unsigned short f2bf(float f) {
  unsigned int u = __float_as_uint(f);
  u += 0x7fffu + ((u >> 16) & 1u);
  return (unsigned short)(u >> 16);
}
__device__ __forceinline__ float bf2f(unsigned short s) {
  return __uint_as_float(((unsigned int)s) << 16);
}

// ws float layout: [0..8191] den, [8192..9215] vsum, scal = wsf+9216:
//   scal[0]=psum, scal[2..5]=counts, scal[9]=done counter
// Zeroed by kernel A's blocks 0..39.

// ---------------- kernel A: zero accum region; normalize -> znb bf16 ------
__global__ __launch_bounds__(256) void norm_kernel(const float* __restrict__ zi,
                                                   const float* __restrict__ zj,
                                                   float* __restrict__ wsf,
                                                   unsigned short* __restrict__ znb) {
  if (blockIdx.x < 40) wsf[blockIdx.x * 256 + threadIdx.x] = 0.f;
  const int lane = threadIdx.x & 63, wave = threadIdx.x >> 6;
  const int i = blockIdx.x * 4 + wave;

  float4 a = ((const float4*)(zi + (size_t)i * DD))[lane];
  float4 b = ((const float4*)(zj + (size_t)i * DD))[lane];
  float sa = a.x * a.x + a.y * a.y + a.z * a.z + a.w * a.w;
  float sb = b.x * b.x + b.y * b.y + b.z * b.z + b.w * b.w;
#pragma unroll
  for (int m = 32; m >= 1; m >>= 1) {
    sa += __shfl_xor(sa, m);
    sb += __shfl_xor(sb, m);
  }
  float ra = 1.0f / fmaxf(sqrtf(sa), 1e-8f);
  float rb = 1.0f / fmaxf(sqrtf(sb), 1e-8f);
  ushort4 oa, ob;
  oa.x = f2bf(a.x * ra); oa.y = f2bf(a.y * ra); oa.z = f2bf(a.z * ra); oa.w = f2bf(a.w * ra);
  ob.x = f2bf(b.x * rb); ob.y = f2bf(b.y * rb); ob.z = f2bf(b.z * rb); ob.w = f2bf(b.w * rb);
  ((ushort4*)(znb + (size_t)i * DD))[lane] = oa;
  ((ushort4*)(znb + (size_t)(i + NB) * DD))[lane] = ob;
}

// ---------------- kernel B: gsum blocks + one tile per block + tail -------
// R6 post-mortem: the runtime LDS pointer (Bb = diag ? As : Bs) broke the
// compiler's no-alias proof between the frag ds_reads and the concurrent
// global_load_lds staging -> serialized ds_read->MFMA chains, 2.5x per-tile
// stall (R4-R6 all hit it). Fix: ALWAYS stage both panels; B-frags read the
// fixed Bs symbol. Diag tiles redundantly stage the same panel into Bs
// (64/2080 tiles, ~0.5MB extra L2 traffic - noise).
__global__ __launch_bounds__(256, 3) void main_kernel(const int* __restrict__ sf,
                                                      float* __restrict__ wsf,
                                                      const unsigned short* __restrict__ znb,
                                                      float* __restrict__ out) {
  __shared__ __align__(16) unsigned short As[2][4096];  // 2 x 8KB
  __shared__ __align__(16) unsigned short Bs[2][4096];
  __shared__ float sred[32];
  __shared__ int sh_last;

  float* den = wsf;
  float* vsum = wsf + 8192;
  float* scal = wsf + 9216;
  unsigned* done = (unsigned*)(scal + 9);

  const int tid = threadIdx.x;
  const int lane = tid & 63, wave = tid >> 6;

  if (blockIdx.x < GSUM_BLOCKS) {
    // ---- gsum role: 256 rows each (znb valid across kernel boundary) ----
    const int r0 = blockIdx.x * 256;
    {
      int g = sf[r0 + tid];
#pragma unroll
      for (int q = 0; q < 4; ++q) {
        unsigned long long m = __ballot(g == q);
        if (lane == 0) unsafeAtomicAdd(&scal[2 + q], (float)__popcll(m));
      }
    }
    float acc[4][4];
#pragma unroll
    for (int q = 0; q < 4; ++q)
#pragma unroll
      for (int e = 0; e < 4; ++e) acc[q][e] = 0.f;
    const int rw = r0 + wave * 64;
    for (int k = 0; k < 64; ++k) {
      int row = rw + k;
      int g = sf[row];
      ushort4 v = ((const ushort4*)(znb + (size_t)row * DD))[lane];
      float f0 = bf2f(v.x), f1 = bf2f(v.y), f2 = bf2f(v.z), f3 = bf2f(v.w);
#pragma unroll
      for (int q = 0; q < 4; ++q) {
        acc[q][0] += (g == q) ? f0 : 0.f;
        acc[q][1] += (g == q) ? f1 : 0.f;
        acc[q][2] += (g == q) ? f2 : 0.f;
        acc[q][3] += (g == q) ? f3 : 0.f;
      }
    }
#pragma unroll
    for (int q = 0; q < 4; ++q)
#pragma unroll
      for (int e = 0; e < 4; ++e)
        unsafeAtomicAdd(&vsum[q * DD + lane * 4 + e], acc[q][e]);
  } else {
    // ---- one symmetric den tile (inner loop shape == R1 den_kernel) ----
    unsigned t = blockIdx.x - GSUM_BLOCKS;
    unsigned tr = 0;
    while (t >= 64u - tr) { t -= 64u - tr; ++tr; }
    unsigned tc = tr + t;
    const bool diag = (tr == tc);
    const size_t rowbase = (size_t)tr * 128, colbase = (size_t)tc * 128;

    const int u = lane >> 3;
    const int cp = (lane & 7) ^ u;
    const int ri = 2 * u + (cp >> 2);
    const int kelem = (cp & 3) * 8;
    const int slot = ((((lane & 1) << 2) | (lane >> 4)) ^ ((lane >> 1) & 7));
    const int fragoff = ((lane & 15) >> 1) * 128 + slot * 16;
    const int wrow = wave & 1, wcol = wave >> 1;

    f32x4 zero = {0.f, 0.f, 0.f, 0.f};
    f32x4 acc[4][4];
#pragma unroll
    for (int i = 0; i < 4; ++i)
#pragma unroll
      for (int j = 0; j < 4; ++j) acc[i][j] = zero;

    auto stage = [&](int kt, int buf) {
#pragma unroll
      for (int j = 0; j < 2; ++j) {
        int is = wave * 2 + j;
        const unsigned short* gpa = znb + (rowbase + is * 16 + ri) * DD + kt * 32 + kelem;
        __builtin_amdgcn_global_load_lds((gvoid_t*)gpa, (lvoid_t*)&As[buf][is * 512], 16, 0, 0);
        const unsigned short* gpb = znb + (colbase + is * 16 + ri) * DD + kt * 32 + kelem;
        __builtin_amdgcn_global_load_lds((gvoid_t*)gpb, (lvoid_t*)&Bs[buf][is * 512], 16, 0, 0);
      }
    };

    stage(0, 0);
    __syncthreads();
#pragma unroll
    for (int kt = 0; kt < 8; ++kt) {
      if (kt < 7) stage(kt + 1, (kt + 1) & 1);
      const int buf = kt & 1;
      short8 af[4], bfr[4];
#pragma unroll
      for (int mi = 0; mi < 4; ++mi)
        af[mi] = *(const short8*)((const char*)&As[buf][0] + wrow * 4096 + mi * 1024 + fragoff);
#pragma unroll
      for (int ni = 0; ni < 4; ++ni)
        bfr[ni] = *(const short8*)((const char*)&Bs[buf][0] + wcol * 4096 + ni * 1024 + fragoff);
#pragma unroll
      for (int mi = 0; mi < 4; ++mi)
#pragma unroll
        for (int ni = 0; ni < 4; ++ni)
          acc[mi][ni] = __builtin_amdgcn_mfma_f32_16x16x32_bf16(af[mi], bfr[ni], acc[mi][ni], 0, 0, 0);
      __syncthreads();
    }

    // epilogue: e = exp(2S); row sums always; col sums for off-diag tiles.
    // C layout: col = lane&15, row = (lane>>4)*4 + reg.
    float rsum[4][4];
    float csum[4] = {0.f, 0.f, 0.f, 0.f};
#pragma unroll
    for (int mi = 0; mi < 4; ++mi)
#pragma unroll
      for (int r = 0; r < 4; ++r) rsum[mi][r] = 0.f;
#pragma unroll
    for (int mi = 0; mi < 4; ++mi)
#pragma unroll
      for (int ni = 0; ni < 4; ++ni)
#pragma unroll
        for (int r = 0; r < 4; ++r) {
          float e = __expf(2.0f * acc[mi][ni][r]);
          rsum[mi][r] += e;
          csum[ni] += e;
        }
#pragma unroll
    for (int m = 1; m < 16; m <<= 1)
#pragma unroll
      for (int mi = 0; mi < 4; ++mi)
#pragma unroll
        for (int r = 0; r < 4; ++r) rsum[mi][r] += __shfl_xor(rsum[mi][r], m);
    if ((lane & 15) == 0) {
      int h = lane >> 4;
#pragma unroll
      for (int mi = 0; mi < 4; ++mi)
#pragma unroll
        for (int r = 0; r < 4; ++r)
          unsafeAtomicAdd(&den[rowbase + wrow * 64 + mi * 16 + h * 4 + r], rsum[mi][r]);
    }
    if (!diag) {
#pragma unroll
      for (int m = 16; m < 64; m <<= 1)
#pragma unroll
        for (int ni = 0; ni < 4; ++ni) csum[ni] += __shfl_xor(csum[ni], m);
      if (lane < 16) {
#pragma unroll
        for (int ni = 0; ni < 4; ++ni)
          unsafeAtomicAdd(&den[colbase + wcol * 64 + ni * 16 + lane], csum[ni]);
      }
    }
    // pos trace: tiles (tr, tr+32) hold S[i][i+B] on their local diagonal.
    if (tc == tr + 32u && wrow == wcol) {
      float tacc = 0.f;
      int c = lane & 15, quad = lane >> 4;
      bool sel = (c >> 2) == quad;
#pragma unroll
      for (int mi = 0; mi < 4; ++mi)
#pragma unroll
        for (int r = 0; r < 4; ++r)
          tacc += (sel && ((c & 3) == r)) ? acc[mi][mi][r] : 0.f;
#pragma unroll
      for (int m = 32; m >= 1; m >>= 1) tacc += __shfl_xor(tacc, m);
      if (lane == 0) unsafeAtomicAdd(&scal[0], tacc);
    }
  }

  // ---- arrive (RELEASE only); last block computes the tail ---------------
  __syncthreads();
  if (tid == 0) {
    unsigned old = __hip_atomic_fetch_add(done, 1u, __ATOMIC_RELEASE, __HIP_MEMORY_SCOPE_AGENT);
    sh_last = (old == gridDim.x - 1) ? 1 : 0;
  }
  __syncthreads();
  if (!sh_last) return;
  __builtin_amdgcn_fence(__ATOMIC_ACQUIRE, "agent");  // single buffer_inv, last block only

  // tail: log-reduce den, fairness from vsum, finalize
  const float e2 = __expf(2.0f);
  float ls = 0.f;
  for (int i = tid; i < TWOB; i += 256) ls += __logf(den[i] - e2);
#pragma unroll
  for (int m = 32; m >= 1; m >>= 1) ls += __shfl_xor(ls, m);
  if (lane == 0) sred[wave] = ls;
  float gp[4];
#pragma unroll
  for (int g = 0; g < 4; ++g) {
    float v = vsum[g * DD + tid];
    gp[g] = v * v;
#pragma unroll
    for (int m = 32; m >= 1; m >>= 1) gp[g] += __shfl_xor(gp[g], m);
  }
  if (lane == 0) {
#pragma unroll
    for (int g = 0; g < 4; ++g) sred[4 + wave * 4 + g] = gp[g];
  }
  __syncthreads();
  if (tid == 0) {
    float lsum = sred[0] + sred[1] + sred[2] + sred[3];
    float psum = scal[0];
    float contrastive = (lsum - 4.0f * psum) / (float)TWOB;
    float fsum = 0.f;
    int uniq = 0;
#pragma unroll
    for (int q = 0; q < 4; ++q) {
      float gsq = sred[4 + q] + sred[8 + q] + sred[12 + q] + sred[16 + q];
      float c = scal[2 + q];
      if (c > 0.5f) uniq++;
      if (c > 1.5f) fsum += gsq / (c * (c - 1.0f));
    }
    out[0] = contrastive + 0.1f * (fsum / (uniq > 0 ? (float)uniq : 1.0f));
  }
}

extern "C" void kernel_launch(void* const* d_in, const int* in_sizes, int n_in,
                              void* d_out, int out_size, void* d_ws, size_t ws_size,
                              hipStream_t stream) {
  const float* zi = (const float*)d_in[0];
  const float* zj = (const float*)d_in[1];
  const int* sf = (const int*)d_in[2];
  float* out = (float*)d_out;
  char* ws = (char*)d_ws;
  float* wsf = (float*)ws;                              // den/vsum/scal region
  unsigned short* znb = (unsigned short*)(ws + 65536);  // 8192x256 bf16 (4MB)

  hipLaunchKernelGGL(norm_kernel, dim3(1024), dim3(256), 0, stream, zi, zj, wsf, znb);
  hipLaunchKernelGGL(main_kernel, dim3(GRID_B), dim3(256), 0, stream, sf, wsf, znb, out);
}

// Round 8
// 134.123 us; speedup vs baseline: 1.0483x; 1.0483x over previous
//
#include <hip/hip_runtime.h>
#include <hip/hip_bf16.h>

typedef __attribute__((ext_vector_type(8))) short short8;
typedef __attribute__((ext_vector_type(4))) float f32x4;
typedef __attribute__((address_space(1))) const void gvoid_t;
typedef __attribute__((address_space(3))) void lvoid_t;

#define NB 4096   // B
#define DD 256    // D
#define TWOB 8192
#define NTILES 2080u   // 64*65/2 symmetric 128x128 tiles
#define GSUM_BLOCKS 16
#define GRID_B (NTILES + GSUM_BLOCKS)   // 2096 = 48*33 + 16*32

__device__ __forceinline__ unsigned short f2bf(float f) {
  unsigned int u = __float_as_uint(f);
  u += 0x7fffu + ((u >> 16) & 1u);
  return (unsigned short)(u >> 16);
}
__device__ __forceinline__ float bf2f(unsigned short s) {
  return __uint_as_float(((unsigned int)s) << 16);
}

// ws float layout: [0..8191] den, [8192..9215] vsum, scal = wsf+9216 (16):
//   scal[0]=psum, scal[2..5]=counts
// arrive tree (uint): leaves at wsf+9232, 64 counters spaced 32 uints (128B
// cachelines); root at wsf+11280. Zeroed by kernel A blocks 0..47.
// R7 post-mortem: a SINGLE agent-scope fetch_add (with return) per block exit
// serialized at ~40ns/RMW at the coherence point (2096 x 40ns = 84us = the
// whole wall; blocks stall in exit-wait holding CU slots). Hierarchical
// arrive caps per-line contention at 64.

// ---------------- kernel A: zero accum region; normalize -> znb bf16 ------
__global__ __launch_bounds__(256) void norm_kernel(const float* __restrict__ zi,
                                                   const float* __restrict__ zj,
                                                   float* __restrict__ wsf,
                                                   unsigned short* __restrict__ znb) {
  if (blockIdx.x < 48) wsf[blockIdx.x * 256 + threadIdx.x] = 0.f;
  const int lane = threadIdx.x & 63, wave = threadIdx.x >> 6;
  const int i = blockIdx.x * 4 + wave;

  float4 a = ((const float4*)(zi + (size_t)i * DD))[lane];
  float4 b = ((const float4*)(zj + (size_t)i * DD))[lane];
  float sa = a.x * a.x + a.y * a.y + a.z * a.z + a.w * a.w;
  float sb = b.x * b.x + b.y * b.y + b.z * b.z + b.w * b.w;
#pragma unroll
  for (int m = 32; m >= 1; m >>= 1) {
    sa += __shfl_xor(sa, m);
    sb += __shfl_xor(sb, m);
  }
  float ra = 1.0f / fmaxf(sqrtf(sa), 1e-8f);
  float rb = 1.0f / fmaxf(sqrtf(sb), 1e-8f);
  ushort4 oa, ob;
  oa.x = f2bf(a.x * ra); oa.y = f2bf(a.y * ra); oa.z = f2bf(a.z * ra); oa.w = f2bf(a.w * ra);
  ob.x = f2bf(b.x * rb); ob.y = f2bf(b.y * rb); ob.z = f2bf(b.z * rb); ob.w = f2bf(b.w * rb);
  ((ushort4*)(znb + (size_t)i * DD))[lane] = oa;
  ((ushort4*)(znb + (size_t)(i + NB) * DD))[lane] = ob;
}

// ---------------- kernel B: gsum blocks + one tile per block + tail -------
__global__ __launch_bounds__(256, 3) void main_kernel(const int* __restrict__ sf,
                                                      float* __restrict__ wsf,
                                                      const unsigned short* __restrict__ znb,
                                                      float* __restrict__ out) {
  __shared__ __align__(16) unsigned short As[2][4096];  // 2 x 8KB
  __shared__ __align__(16) unsigned short Bs[2][4096];
  __shared__ float sred[32];
  __shared__ int sh_last;

  float* den = wsf;
  float* vsum = wsf + 8192;
  float* scal = wsf + 9216;
  unsigned* leaves = (unsigned*)(wsf + 9232);  // 64 counters, stride 32 uints
  unsigned* root = (unsigned*)(wsf + 11280);

  const int tid = threadIdx.x;
  const int lane = tid & 63, wave = tid >> 6;

  if (blockIdx.x < GSUM_BLOCKS) {
    // ---- gsum role: 256 rows each (znb valid across kernel boundary) ----
    const int r0 = blockIdx.x * 256;
    {
      int g = sf[r0 + tid];
#pragma unroll
      for (int q = 0; q < 4; ++q) {
        unsigned long long m = __ballot(g == q);
        if (lane == 0) unsafeAtomicAdd(&scal[2 + q], (float)__popcll(m));
      }
    }
    float acc[4][4];
#pragma unroll
    for (int q = 0; q < 4; ++q)
#pragma unroll
      for (int e = 0; e < 4; ++e) acc[q][e] = 0.f;
    const int rw = r0 + wave * 64;
    for (int k = 0; k < 64; ++k) {
      int row = rw + k;
      int g = sf[row];
      ushort4 v = ((const ushort4*)(znb + (size_t)row * DD))[lane];
      float f0 = bf2f(v.x), f1 = bf2f(v.y), f2 = bf2f(v.z), f3 = bf2f(v.w);
#pragma unroll
      for (int q = 0; q < 4; ++q) {
        acc[q][0] += (g == q) ? f0 : 0.f;
        acc[q][1] += (g == q) ? f1 : 0.f;
        acc[q][2] += (g == q) ? f2 : 0.f;
        acc[q][3] += (g == q) ? f3 : 0.f;
      }
    }
#pragma unroll
    for (int q = 0; q < 4; ++q)
#pragma unroll
      for (int e = 0; e < 4; ++e)
        unsafeAtomicAdd(&vsum[q * DD + lane * 4 + e], acc[q][e]);
  } else {
    // ---- one symmetric den tile ----------------------------------------
    unsigned t = blockIdx.x - GSUM_BLOCKS;
    unsigned tr = 0;
    while (t >= 64u - tr) { t -= 64u - tr; ++tr; }
    unsigned tc = tr + t;
    const bool diag = (tr == tc);
    const size_t rowbase = (size_t)tr * 128, colbase = (size_t)tc * 128;

    const int u = lane >> 3;
    const int cp = (lane & 7) ^ u;
    const int ri = 2 * u + (cp >> 2);
    const int kelem = (cp & 3) * 8;
    const int slot = ((((lane & 1) << 2) | (lane >> 4)) ^ ((lane >> 1) & 7));
    const int fragoff = ((lane & 15) >> 1) * 128 + slot * 16;
    const int wrow = wave & 1, wcol = wave >> 1;

    f32x4 zero = {0.f, 0.f, 0.f, 0.f};
    f32x4 acc[4][4];
#pragma unroll
    for (int i = 0; i < 4; ++i)
#pragma unroll
      for (int j = 0; j < 4; ++j) acc[i][j] = zero;

    auto stage = [&](int kt, int buf) {
#pragma unroll
      for (int j = 0; j < 2; ++j) {
        int is = wave * 2 + j;
        const unsigned short* gpa = znb + (rowbase + is * 16 + ri) * DD + kt * 32 + kelem;
        __builtin_amdgcn_global_load_lds((gvoid_t*)gpa, (lvoid_t*)&As[buf][is * 512], 16, 0, 0);
        const unsigned short* gpb = znb + (colbase + is * 16 + ri) * DD + kt * 32 + kelem;
        __builtin_amdgcn_global_load_lds((gvoid_t*)gpb, (lvoid_t*)&Bs[buf][is * 512], 16, 0, 0);
      }
    };

    stage(0, 0);
    __syncthreads();
#pragma unroll
    for (int kt = 0; kt < 8; ++kt) {
      if (kt < 7) stage(kt + 1, (kt + 1) & 1);
      const int buf = kt & 1;
      short8 af[4], bfr[4];
#pragma unroll
      for (int mi = 0; mi < 4; ++mi)
        af[mi] = *(const short8*)((const char*)&As[buf][0] + wrow * 4096 + mi * 1024 + fragoff);
#pragma unroll
      for (int ni = 0; ni < 4; ++ni)
        bfr[ni] = *(const short8*)((const char*)&Bs[buf][0] + wcol * 4096 + ni * 1024 + fragoff);
#pragma unroll
      for (int mi = 0; mi < 4; ++mi)
#pragma unroll
        for (int ni = 0; ni < 4; ++ni)
          acc[mi][ni] = __builtin_amdgcn_mfma_f32_16x16x32_bf16(af[mi], bfr[ni], acc[mi][ni], 0, 0, 0);
      __syncthreads();
    }

    // epilogue: e = exp(2S); row sums always; col sums for off-diag tiles.
    // C layout: col = lane&15, row = (lane>>4)*4 + reg.
    float rsum[4][4];
    float csum[4] = {0.f, 0.f, 0.f, 0.f};
#pragma unroll
    for (int mi = 0; mi < 4; ++mi)
#pragma unroll
      for (int r = 0; r < 4; ++r) rsum[mi][r] = 0.f;
#pragma unroll
    for (int mi = 0; mi < 4; ++mi)
#pragma unroll
      for (int ni = 0; ni < 4; ++ni)
#pragma unroll
        for (int r = 0; r < 4; ++r) {
          float e = __expf(2.0f * acc[mi][ni][r]);
          rsum[mi][r] += e;
          csum[ni] += e;
        }
#pragma unroll
    for (int m = 1; m < 16; m <<= 1)
#pragma unroll
      for (int mi = 0; mi < 4; ++mi)
#pragma unroll
        for (int r = 0; r < 4; ++r) rsum[mi][r] += __shfl_xor(rsum[mi][r], m);
    if ((lane & 15) == 0) {
      int h = lane >> 4;
#pragma unroll
      for (int mi = 0; mi < 4; ++mi)
#pragma unroll
        for (int r = 0; r < 4; ++r)
          unsafeAtomicAdd(&den[rowbase + wrow * 64 + mi * 16 + h * 4 + r], rsum[mi][r]);
    }
    if (!diag) {
#pragma unroll
      for (int m = 16; m < 64; m <<= 1)
#pragma unroll
        for (int ni = 0; ni < 4; ++ni) csum[ni] += __shfl_xor(csum[ni], m);
      if (lane < 16) {
#pragma unroll
        for (int ni = 0; ni < 4; ++ni)
          unsafeAtomicAdd(&den[colbase + wcol * 64 + ni * 16 + lane], csum[ni]);
      }
    }
    // pos trace: tiles (tr, tr+32) hold S[i][i+B] on their local diagonal.
    if (tc == tr + 32u && wrow == wcol) {
      float tacc = 0.f;
      int c = lane & 15, quad = lane >> 4;
      bool sel = (c >> 2) == quad;
#pragma unroll
      for (int mi = 0; mi < 4; ++mi)
#pragma unroll
        for (int r = 0; r < 4; ++r)
          tacc += (sel && ((c & 3) == r)) ? acc[mi][mi][r] : 0.f;
#pragma unroll
      for (int m = 32; m >= 1; m >>= 1) tacc += __shfl_xor(tacc, m);
      if (lane == 0) unsafeAtomicAdd(&scal[0], tacc);
    }
  }

  // ---- hierarchical arrive: leaf (<=33 RMWs/line) then root (64 RMWs) ----
  __syncthreads();
  if (tid == 0) {
    int g = blockIdx.x & 63;
    unsigned tgt = (g < 48) ? 33u : 32u;  // 2096 = 48*33 + 16*32
    unsigned old = __hip_atomic_fetch_add(&leaves[g * 32], 1u, __ATOMIC_RELEASE,
                                          __HIP_MEMORY_SCOPE_AGENT);
    int last = 0;
    if (old == tgt - 1u) {
      unsigned ro = __hip_atomic_fetch_add(root, 1u, __ATOMIC_RELEASE,
                                           __HIP_MEMORY_SCOPE_AGENT);
      last = (ro == 63u) ? 1 : 0;
    }
    sh_last = last;
  }
  __syncthreads();
  if (!sh_last) return;
  __builtin_amdgcn_fence(__ATOMIC_ACQUIRE, "agent");  // single buffer_inv, last block only

  // tail: log-reduce den, fairness from vsum, finalize
  const float e2 = __expf(2.0f);
  float ls = 0.f;
  for (int i = tid; i < TWOB; i += 256) ls += __logf(den[i] - e2);
#pragma unroll
  for (int m = 32; m >= 1; m >>= 1) ls += __shfl_xor(ls, m);
  if (lane == 0) sred[wave] = ls;
  float gp[4];
#pragma unroll
  for (int g = 0; g < 4; ++g) {
    float v = vsum[g * DD + tid];
    gp[g] = v * v;
#pragma unroll
    for (int m = 32; m >= 1; m >>= 1) gp[g] += __shfl_xor(gp[g], m);
  }
  if (lane == 0) {
#pragma unroll
    for (int g = 0; g < 4; ++g) sred[4 + wave * 4 + g] = gp[g];
  }
  __syncthreads();
  if (tid == 0) {
    float lsum = sred[0] + sred[1] + sred[2] + sred[3];
    float psum = scal[0];
    float contrastive = (lsum - 4.0f * psum) / (float)TWOB;
    float fsum = 0.f;
    int uniq = 0;
#pragma unroll
    for (int q = 0; q < 4; ++q) {
      float gsq = sred[4 + q] + sred[8 + q] + sred[12 + q] + sred[16 + q];
      float c = scal[2 + q];
      if (c > 0.5f) uniq++;
      if (c > 1.5f) fsum += gsq / (c * (c - 1.0f));
    }
    out[0] = contrastive + 0.1f * (fsum / (uniq > 0 ? (float)uniq : 1.0f));
  }
}

extern "C" void kernel_launch(void* const* d_in, const int* in_sizes, int n_in,
                              void* d_out, int out_size, void* d_ws, size_t ws_size,
                              hipStream_t stream) {
  const float* zi = (const float*)d_in[0];
  const float* zj = (const float*)d_in[1];
  const int* sf = (const int*)d_in[2];
  float* out = (float*)d_out;
  char* ws = (char*)d_ws;
  float* wsf = (float*)ws;                              // den/vsum/scal/arrive region
  unsigned short* znb = (unsigned short*)(ws + 65536);  // 8192x256 bf16 (4MB)

  hipLaunchKernelGGL(norm_kernel, dim3(1024), dim3(256), 0, stream, zi, zj, wsf, znb);
  hipLaunchKernelGGL(main_kernel, dim3(GRID_B), dim3(256), 0, stream, sf, wsf, znb, out);
}